// Round 1
// baseline (372.916 us; speedup 1.0000x reference)
//
#include <hip/hip_runtime.h>
#include <stdint.h>

// Problem constants (fixed by reference)
#define TP_      8
#define M_DIM    4096
#define K_DIM    8192
#define N_DIM    1024      // N_LOCAL
#define KL_      1024      // K_LOCAL
#define BM       256
#define BN       256
#define BK       32
#define SPLITK   4
#define KSLICE   (K_DIM / SPLITK)   // 2048
#define NSTEP    (KSLICE / BK)      // 64
#define MN4      (M_DIM * N_DIM / 4)

typedef _Float16 f16;
typedef f16 f16x8 __attribute__((ext_vector_type(8)));
typedef float f32x4 __attribute__((ext_vector_type(4)));

// lgkm-only barrier: ds_writes drained + join; NO vmcnt drain (staging loads
// are reg-destined and prefetched one K-step ahead; compiler counts their
// waits precisely at the consuming cvt). Memory-clobber fences on both sides
// so LDS ops cannot be scheduled across the barrier (s_barrier builtin alone
// is not an IR-level memory fence).
#define BARRIER() do { \
    asm volatile("s_waitcnt lgkmcnt(0)" ::: "memory"); \
    __builtin_amdgcn_s_barrier(); \
    asm volatile("" ::: "memory"); \
} while (0)

// ---------- fused kernel: gather-A + convert + 256^2 split-K GEMM ----------
// Fragment-major LDS layout (validated in prior rounds): chunk = 16-row group
// (A) / 16-col group (B); chunk holds 512 halfs; lane l's 16B slot =
// X[g*16 + (l&15)][ (l>>4)*8 .. +8 ) of the 32-wide k-window.
// Double-buffered: sm[buf][chunk*512 + ...], A chunks 0..15, B chunks 16..31.
__global__ __launch_bounds__(512, 2) void gemm_fused_kernel(
        const float* __restrict__ act,      // (TP, M, KL) fp32
        const float* __restrict__ W,        // (K, N) fp32
        float* __restrict__ part) {         // (SPLITK, M, N) fp32
    __shared__ f16 sm[2][32 * 512];         // 2 x 32KB

    const int tid  = threadIdx.x;
    const int w    = tid >> 6;              // wave 0..7  (2M x 4N)
    const int lane = tid & 63;
    const int q    = lane >> 4;
    const int rr   = lane & 15;
    const int wr   = w >> 2;                // 0..1
    const int wc   = w & 3;                 // 0..3

    // staging decode: thread owns 16 consecutive k of one A-row and one B-col
    const int rt = tid >> 1;                // 0..255 : A row / B col within tile
    const int hh = tid & 1;                 // k-half (16 floats each)

    // block decode + XCD swizzle: xcd = (z<<1)|(mb&1) -> per XCD: one z,
    // 8 mb panels (A unique per XCD), all 4 nb (A reused x4 in L2).
    const int id   = blockIdx.x;            // 0..255
    const int xcd  = id & 7;
    const int slot = id >> 3;               // 0..31
    const int z    = xcd >> 1;              // 0..3
    const int mb   = (slot >> 2) * 2 + (xcd & 1);   // 0..15
    const int nb   = slot & 3;              // 0..3
    const int row0 = mb * BM;
    const int col0 = nb * BN;
    const int kb   = z * KSLICE;

    float4 aa[4];                           // staged A: 16 fp32
    float  bb[16];                          // staged B: 16 fp32 (column gather)

    f32x4 acc[8][4];
    #pragma unroll
    for (int m = 0; m < 8; m++)
        #pragma unroll
        for (int n = 0; n < 4; n++)
            acc[m][n] = (f32x4){0.f, 0.f, 0.f, 0.f};

    const size_t aRowBase = (size_t)(row0 + rt) * KL_ + hh * 16;
    const float* wColBase = W + col0 + rt;

// A: 4x dwordx4 (64B contiguous of one row; 32-aligned k-window stays in one
// shard since KL%32==0). B: 16x dword column gather — per instruction the
// wave covers 2 rows x 128B contiguous segments.
#define LOADT(step) do { \
    const int kk_ = kb + (step) * BK; \
    const int r_  = kk_ >> 10; \
    const int kl_ = kk_ & (KL_ - 1); \
    const float* ap = act + (size_t)r_ * ((size_t)M_DIM * KL_) + aRowBase + kl_; \
    _Pragma("unroll") \
    for (int i = 0; i < 4; i++) aa[i] = ((const float4*)ap)[i]; \
    const float* wp = wColBase + (size_t)(kk_ + hh * 16) * N_DIM; \
    _Pragma("unroll") \
    for (int j = 0; j < 16; j++) bb[j] = wp[(size_t)j * N_DIM]; \
} while (0)

// cvt fp32->fp16 + 4x ds_write_b128 into fragment-major slots.
// Write banks: (rt&7)*16-byte positions -> 8 lanes per bank-quad = minimum
// phases, conflict-free.
#define CVTWRITE(buf) do { \
    f16x8 u0, u1, v0, v1; \
    u0[0]=(f16)aa[0].x; u0[1]=(f16)aa[0].y; u0[2]=(f16)aa[0].z; u0[3]=(f16)aa[0].w; \
    u0[4]=(f16)aa[1].x; u0[5]=(f16)aa[1].y; u0[6]=(f16)aa[1].z; u0[7]=(f16)aa[1].w; \
    u1[0]=(f16)aa[2].x; u1[1]=(f16)aa[2].y; u1[2]=(f16)aa[2].z; u1[3]=(f16)aa[2].w; \
    u1[4]=(f16)aa[3].x; u1[5]=(f16)aa[3].y; u1[6]=(f16)aa[3].z; u1[7]=(f16)aa[3].w; \
    _Pragma("unroll") \
    for (int j = 0; j < 8; j++) v0[j] = (f16)bb[j]; \
    _Pragma("unroll") \
    for (int j = 0; j < 8; j++) v1[j] = (f16)bb[8 + j]; \
    f16* dA = &sm[buf][(rt >> 4) * 512]; \
    *(f16x8*)(dA + ((2 * hh)     * 16 + (rt & 15)) * 8) = u0; \
    *(f16x8*)(dA + ((2 * hh + 1) * 16 + (rt & 15)) * 8) = u1; \
    f16* dB = &sm[buf][(16 + (rt >> 4)) * 512]; \
    *(f16x8*)(dB + ((2 * hh)     * 16 + (rt & 15)) * 8) = v0; \
    *(f16x8*)(dB + ((2 * hh + 1) * 16 + (rt & 15)) * 8) = v1; \
} while (0)

// 12x ds_read_b128 (contiguous 1KB per chunk: conflict-free) + 32 MFMA.
#define MFMAT(buf) do { \
    const f16* base_ = sm[buf]; \
    f16x8 bf[4]; \
    _Pragma("unroll") \
    for (int n = 0; n < 4; n++) \
        bf[n] = *(const f16x8*)(base_ + (size_t)(16 + wc * 4 + n) * 512 + lane * 8); \
    _Pragma("unroll") \
    for (int mh = 0; mh < 2; mh++) { \
        f16x8 af[4]; \
        _Pragma("unroll") \
        for (int mi = 0; mi < 4; mi++) \
            af[mi] = *(const f16x8*)(base_ + (size_t)(wr * 8 + mh * 4 + mi) * 512 + lane * 8); \
        _Pragma("unroll") \
        for (int mi = 0; mi < 4; mi++) \
            _Pragma("unroll") \
            for (int n = 0; n < 4; n++) \
                acc[mh * 4 + mi][n] = __builtin_amdgcn_mfma_f32_16x16x32_f16( \
                    af[mi], bf[n], acc[mh * 4 + mi][n], 0, 0, 0); \
    } \
} while (0)

    // ---- pipeline prologue: buf0 <- step0, regs <- step1 ----
    LOADT(0);
    CVTWRITE(0);
    LOADT(1);
    BARRIER();

    // ---- main loop: per step = {write next buf, issue loads t+2, MFMA cur} ----
    // Invariant entering iteration t: buf0 = data t, regs = data t+1.
    #pragma unroll 1
    for (int t = 0; t < NSTEP - 2; t += 2) {
        CVTWRITE(1);          // data t+1 -> buf1
        LOADT(t + 2);         // in flight across MFMA + barrier
        MFMAT(0);             // compute data t
        BARRIER();
        CVTWRITE(0);          // data t+2 -> buf0
        LOADT(t + 3);         // t <= 60 -> max step 63
        MFMAT(1);             // compute data t+1
        BARRIER();
    }
    // tail: buf0 = 62, regs = 63
    CVTWRITE(1);
    MFMAT(0);                 // 62
    BARRIER();
    MFMAT(1);                 // 63

    // ---- epilogue: C/D layout col = lane&15, row = q*4 + reg (validated) ----
    float* Pz = part + (size_t)z * M_DIM * N_DIM;
    #pragma unroll
    for (int m = 0; m < 8; m++) {
        const int gm = row0 + wr * 128 + m * 16 + q * 4;
        #pragma unroll
        for (int n = 0; n < 4; n++) {
            const int gn = col0 + wc * 64 + n * 16 + rr;
            #pragma unroll
            for (int r2 = 0; r2 < 4; r2++)
                __builtin_nontemporal_store(acc[m][n][r2],
                    &Pz[(size_t)(gm + r2) * N_DIM + gn]);
        }
    }
#undef LOADT
#undef CVTWRITE
#undef MFMAT
}

// ---------- kernel 2: reduce 4 partials + bias (unchanged, proven) ----------
__global__ __launch_bounds__(256) void reduce_kernel(
        const float* __restrict__ part, const float* __restrict__ bias,
        float* __restrict__ out) {
    int p = blockIdx.x * 256 + threadIdx.x;
    const float4* P = (const float4*)part;
    float4 s0 = P[p];
    float4 s1 = P[p + MN4];
    float4 s2 = P[p + 2 * MN4];
    float4 s3 = P[p + 3 * MN4];
    float4 b  = ((const float4*)bias)[p & (N_DIM / 4 - 1)];
    float4 r;
    r.x = s0.x + s1.x + s2.x + s3.x + b.x;
    r.y = s0.y + s1.y + s2.y + s3.y + b.y;
    r.z = s0.z + s1.z + s2.z + s3.z + b.z;
    r.w = s0.w + s1.w + s2.w + s3.w + b.w;
    ((float4*)out)[p] = r;
}

// ---------- fallback (only if ws too small): naive fp32 tiled GEMM ----------
__global__ void gemm_fallback_kernel(const float* __restrict__ act,
                                     const float* __restrict__ W,
                                     const float* __restrict__ bias,
                                     float* __restrict__ out) {
    __shared__ float sA2[32][33];
    __shared__ float sB2[32][33];
    int tx = threadIdx.x, ty = threadIdx.y;
    int m = blockIdx.y * 32 + ty;
    int n = blockIdx.x * 32 + tx;
    float acc = 0.f;
    for (int kt = 0; kt < K_DIM; kt += 32) {
        int ka = kt + tx;
        int r = ka >> 10, kl = ka & (KL_ - 1);
        sA2[ty][tx] = act[((size_t)r * M_DIM + m) * KL_ + kl];
        sB2[ty][tx] = W[(size_t)(kt + ty) * N_DIM + n];
        __syncthreads();
        #pragma unroll
        for (int kk = 0; kk < 32; kk++) acc += sA2[ty][kk] * sB2[kk][tx];
        __syncthreads();
    }
    out[(size_t)m * N_DIM + n] = acc + bias[n];
}

extern "C" void kernel_launch(void* const* d_in, const int* in_sizes, int n_in,
                              void* d_out, int out_size, void* d_ws, size_t ws_size,
                              hipStream_t stream) {
    const float* all_act = (const float*)d_in[0];
    const float* local_W = (const float*)d_in[1];
    const float* bias    = (const float*)d_in[2];
    float* out = (float*)d_out;

    const size_t partBytes = (size_t)SPLITK * M_DIM * N_DIM * sizeof(float);  // 67.1 MB

    if (ws_size < partBytes) {
        gemm_fallback_kernel<<<dim3(N_DIM / 32, M_DIM / 32), dim3(32, 32), 0, stream>>>(
            all_act, local_W, bias, out);
        return;
    }

    float* part = (float*)d_ws;
    gemm_fused_kernel<<<256, 512, 0, stream>>>(all_act, local_W, part);
    reduce_kernel<<<MN4 / 256, 256, 0, stream>>>(part, bias, out);
}

// Round 2
// 301.308 us; speedup vs baseline: 1.2377x; 1.2377x over previous
//
#include <hip/hip_runtime.h>
#include <stdint.h>

// Problem constants (fixed by reference)
#define TP_      8
#define M_DIM    4096
#define K_DIM    8192
#define N_DIM    1024      // N_LOCAL
#define KL_      1024      // K_LOCAL
#define BM       256
#define BN       256
#define SPLITK   4
#define KSLICE   (K_DIM / SPLITK)   // 2048
#define NT       (KSLICE / 64)      // 32 K-tiles of BK=64
#define MN4      (M_DIM * N_DIM / 4)
#define KCHUNKS  (K_DIM / 32)       // 256 k32-chunks per 16-row group

typedef _Float16 f16;
typedef f16 f16x8 __attribute__((ext_vector_type(8)));
typedef float f32x4 __attribute__((ext_vector_type(4)));

// 8x fp32 -> fp16 (v_cvt_f16_f32, RN)
__device__ __forceinline__ f16x8 cvt8(float4 a, float4 b) {
    f16x8 r;
    r[0] = (f16)a.x; r[1] = (f16)a.y; r[2] = (f16)a.z; r[3] = (f16)a.w;
    r[4] = (f16)b.x; r[5] = (f16)b.y; r[6] = (f16)b.z; r[7] = (f16)b.w;
    return r;
}

// async global->LDS, 16B/lane; dest = wave-uniform base + lane*16 (m104/m108).
// Passing per-lane lds addr is safe: compiler readfirstlanes it (lane0 -> +0).
__device__ __forceinline__ void lds_load16(const void* g, void* l) {
    __builtin_amdgcn_global_load_lds(
        (const __attribute__((address_space(1))) void*)g,
        (__attribute__((address_space(3))) void*)l, 16, 0, 0);
}

// Fragment-major layout (both operands): chunk c = rowgroup*KCHUNKS + k32;
// chunk holds 512 halfs; slot lane*8 = X[group*16 + (lane&15)][k32*32 + (lane>>4)*8 ..+8].
// A wave touching one chunk reads/writes base + lane*16B: ONE 1KB transaction.

// ---------- kernel 1: gather + convert A -> fragment-major fp16 ----------
__global__ __launch_bounds__(256) void conv_a_kernel(
        const float* __restrict__ act, f16* __restrict__ Afrag) {
    const int t = threadIdx.x;
    const int chunkId = blockIdx.x * 4 + (t >> 6);   // 65536 chunks
    const int lane = t & 63;
    const int q  = lane >> 4;
    const int rr = lane & 15;
    const int mg  = chunkId >> 8;                    // m-16-group (KCHUNKS=256)
    const int k32 = chunkId & 255;
    const int k  = k32 * 32 + q * 8;                 // 32-aligned chunk: one shard
    const int r  = k >> 10;
    const int kl = k & (KL_ - 1);
    const int m  = mg * 16 + rr;
    const float4* src = (const float4*)(act + ((size_t)r * M_DIM + m) * KL_ + kl);
    float4 a = src[0], b = src[1];
    *(f16x8*)(Afrag + (size_t)chunkId * 512 + lane * 8) = cvt8(a, b);
}

// ---------- kernel 2: convert + repack W -> fragment-major fp16 ----------
__global__ __launch_bounds__(256) void conv_w_kernel(
        const float* __restrict__ W, f16* __restrict__ Bfrag) {
    __shared__ float tile[64][68];                 // [k][n], pad 68
    const int t  = threadIdx.x;
    const int n0 = blockIdx.x * 64;
    const int k0 = blockIdx.y * 64;
    #pragma unroll
    for (int l = 0; l < 4; l++) {
        int kr = l * 16 + (t >> 4);
        float4 v = *(const float4*)&W[(size_t)(k0 + kr) * N_DIM + n0 + (t & 15) * 4];
        *(float4*)&tile[kr][(t & 15) * 4] = v;
    }
    __syncthreads();
    const int jtl   = t >> 6;
    const int kt32l = (t >> 5) & 1;
    const int u     = t & 31;
    const int rr    = u & 15;
    const int qp    = u >> 4;
    f16x8 h0, h1;
    #pragma unroll
    for (int kk = 0; kk < 8; kk++)
        h0[kk] = (f16)tile[kt32l * 32 + qp * 16 + kk][jtl * 16 + rr];
    #pragma unroll
    for (int kk = 0; kk < 8; kk++)
        h1[kk] = (f16)tile[kt32l * 32 + qp * 16 + 8 + kk][jtl * 16 + rr];
    size_t chunk = (size_t)(n0 / 16 + jtl) * KCHUNKS + (k0 / 32 + kt32l);
    f16* dst = Bfrag + chunk * 512;
    *(f16x8*)(dst + ((2 * qp)     * 16 + rr) * 8) = h0;
    *(f16x8*)(dst + ((2 * qp + 1) * 16 + rr) * 8) = h1;
}

// ---------- kernel 3: 8-phase-style deep-pipelined fragment GEMM ----------
// 256x256 tile, 8 waves (2M x 4N), BK=64 (2 k32), double-buffered 2x64KB LDS.
// Per K-tile: 4 phases x {ds_read subtile, stage 1 segment of tile t+1,
// barrier, setprio(1), 16 MFMA, setprio(0), [vmcnt(4)], barrier}.
// Staging segment = {A or B} x {k2} = 16 chunks = 16KB = 2 global_load_lds/wave.
// vmcnt(4) derivation: consumed segment is always 2 segments (4 loads) older
// than the newest issue -> counted wait, never 0 in the main loop (T4).
__global__ __launch_bounds__(512, 2) void gemm_frag_kernel(
        const f16* __restrict__ Afrag,
        const f16* __restrict__ Bfrag,
        float* __restrict__ part) {               // (SPLITK, M, N) fp32
    __shared__ f16 sm[2][64 * 512];               // 2 x 64KB: A chunks 0..31 (mg*2+k2), B 32..63

    const int tid  = threadIdx.x;
    const int w    = tid >> 6;                    // wave 0..7
    const int lane = tid & 63;
    const int q    = lane >> 4;
    const int rr   = lane & 15;
    const int wr   = w >> 2;                      // 0..1 (M)
    const int wc   = w & 3;                       // 0..3 (N)

    // XCD decode: xcd = (z<<1)|(mb&1). Per XCD: one z (B slice L2-resident),
    // 8 unique mb panels, all 4 nb (A panel reused x4 in L2).
    const int id   = blockIdx.x;                  // 0..255
    const int xcd  = id & 7;
    const int slot = id >> 3;                     // 0..31
    const int z    = xcd >> 1;                    // 0..3
    const int mb   = (slot >> 2) * 2 + (xcd & 1); // 0..15
    const int nb   = slot & 3;                    // 0..3
    const int row0 = mb * BM;
    const int col0 = nb * BN;
    const int kb32 = z * (KSLICE / 32);           // first k32 of this z-slice
    const int mg0  = row0 >> 4;
    const int ng0  = col0 >> 4;

    f32x4 acc[8][4];
    #pragma unroll
    for (int m = 0; m < 8; m++)
        #pragma unroll
        for (int n = 0; n < 4; n++)
            acc[m][n] = (f32x4){0.f, 0.f, 0.f, 0.f};

    f16x8 af[8];   // A fragments of current k2 half (reused across 2 n-phases)
    f16x8 bf[2];   // B fragments of current phase

#define STAGE_A(B_, T_, K2_) do { \
    const int kt32_ = kb32 + 2 * (T_) + (K2_); \
    _Pragma("unroll") \
    for (int j_ = 0; j_ < 2; j_++) { \
        const int mg_ = 2 * w + j_; \
        const f16* g_ = Afrag + ((size_t)(mg0 + mg_) * KCHUNKS + kt32_) * 512 + lane * 8; \
        lds_load16(g_, &sm[B_][(mg_ * 2 + (K2_)) * 512 + lane * 8]); \
    } \
} while (0)

#define STAGE_B(B_, T_, K2_) do { \
    const int kt32_ = kb32 + 2 * (T_) + (K2_); \
    _Pragma("unroll") \
    for (int j_ = 0; j_ < 2; j_++) { \
        const int ng_ = 2 * w + j_; \
        const f16* g_ = Bfrag + ((size_t)(ng0 + ng_) * KCHUNKS + kt32_) * 512 + lane * 8; \
        lds_load16(g_, &sm[B_][(32 + ng_ * 2 + (K2_)) * 512 + lane * 8]); \
    } \
} while (0)

#define READ_A(B_, K2_) do { \
    _Pragma("unroll") \
    for (int mi_ = 0; mi_ < 8; mi_++) \
        af[mi_] = *(const f16x8*)&sm[B_][((wr * 8 + mi_) * 2 + (K2_)) * 512 + lane * 8]; \
} while (0)

#define READ_B(B_, K2_, NH_) do { \
    _Pragma("unroll") \
    for (int ni_ = 0; ni_ < 2; ni_++) \
        bf[ni_] = *(const f16x8*)&sm[B_][(32 + (wc * 4 + (NH_) * 2 + ni_) * 2 + (K2_)) * 512 + lane * 8]; \
} while (0)

#define MFMA16(NH_) do { \
    __builtin_amdgcn_s_setprio(1); \
    _Pragma("unroll") \
    for (int mi_ = 0; mi_ < 8; mi_++) \
        _Pragma("unroll") \
        for (int ni_ = 0; ni_ < 2; ni_++) \
            acc[mi_][(NH_) * 2 + ni_] = __builtin_amdgcn_mfma_f32_16x16x32_f16( \
                af[mi_], bf[ni_], acc[mi_][(NH_) * 2 + ni_], 0, 0, 0); \
    __builtin_amdgcn_s_setprio(0); \
} while (0)

#define BAR() do { \
    asm volatile("" ::: "memory"); \
    __builtin_amdgcn_s_barrier(); \
    asm volatile("" ::: "memory"); \
} while (0)
#define SBAR0() __builtin_amdgcn_sched_barrier(0)
#define VM4() asm volatile("s_waitcnt vmcnt(4)" ::: "memory")
#define VM0() asm volatile("s_waitcnt vmcnt(0)" ::: "memory")

// One K-tile = 4 phases. VMMID_ guards A1/B1 of tile T_ before ph2 reads;
// VMEND_ guards A0/B0 of tile T_+1 before next tile's ph0 reads.
#define TILE(P_, T_, STG_, VMMID_, VMEND_) do { \
    READ_A(P_, 0); READ_B(P_, 0, 0); \
    if (STG_) STAGE_A((P_) ^ 1, (T_) + 1, 0); \
    BAR(); SBAR0(); MFMA16(0); BAR(); \
    READ_B(P_, 0, 1); \
    if (STG_) STAGE_B((P_) ^ 1, (T_) + 1, 0); \
    BAR(); SBAR0(); MFMA16(1); VMMID_; BAR(); \
    READ_A(P_, 1); READ_B(P_, 1, 0); \
    if (STG_) STAGE_A((P_) ^ 1, (T_) + 1, 1); \
    BAR(); SBAR0(); MFMA16(0); BAR(); \
    READ_B(P_, 1, 1); \
    if (STG_) STAGE_B((P_) ^ 1, (T_) + 1, 1); \
    BAR(); SBAR0(); MFMA16(1); VMEND_; BAR(); \
} while (0)

    // ---- prologue: stage tile 0 into buf0; wait for its first half ----
    STAGE_A(0, 0, 0);
    STAGE_B(0, 0, 0);
    STAGE_A(0, 0, 1);
    STAGE_B(0, 0, 1);
    VM4();                   // A0,B0(0) landed (A1,B1(0) still in flight)
    BAR();

    // ---- main loop: tiles 0..30 stage tile t+1; tail tile 31 drains ----
    #pragma unroll 1
    for (int t = 0; t < 30; t += 2) {
        TILE(0, t,     1, VM4(), VM4());
        TILE(1, t + 1, 1, VM4(), VM4());
    }
    TILE(0, 30, 1, VM4(), VM4());
    TILE(1, 31, 0, VM0(), (void)0);   // tail: no staging; drain once mid-tile

    // ---- epilogue: C/D layout col = lane&15, row = q*4 + reg (validated) ----
    float* Pz = part + (size_t)z * M_DIM * N_DIM;
    #pragma unroll
    for (int m = 0; m < 8; m++) {
        const int gm = row0 + wr * 128 + m * 16 + q * 4;
        #pragma unroll
        for (int n = 0; n < 4; n++) {
            const int gn = col0 + wc * 64 + n * 16 + rr;
            #pragma unroll
            for (int r2 = 0; r2 < 4; r2++)
                Pz[(size_t)(gm + r2) * N_DIM + gn] = acc[m][n][r2];
        }
    }
#undef STAGE_A
#undef STAGE_B
#undef READ_A
#undef READ_B
#undef MFMA16
#undef BAR
#undef SBAR0
#undef VM4
#undef VM0
#undef TILE
}

// ---------- kernel 4: reduce 4 partials + bias ----------
__global__ __launch_bounds__(256) void reduce_kernel(
        const float* __restrict__ part, const float* __restrict__ bias,
        float* __restrict__ out) {
    int p = blockIdx.x * 256 + threadIdx.x;
    const float4* P = (const float4*)part;
    float4 s0 = P[p];
    float4 s1 = P[p + MN4];
    float4 s2 = P[p + 2 * MN4];
    float4 s3 = P[p + 3 * MN4];
    float4 b  = ((const float4*)bias)[p & (N_DIM / 4 - 1)];
    float4 r;
    r.x = s0.x + s1.x + s2.x + s3.x + b.x;
    r.y = s0.y + s1.y + s2.y + s3.y + b.y;
    r.z = s0.z + s1.z + s2.z + s3.z + b.z;
    r.w = s0.w + s1.w + s2.w + s3.w + b.w;
    ((float4*)out)[p] = r;
}

// ---------- fallback (only if ws too small): naive fp32 tiled GEMM ----------
__global__ void gemm_fallback_kernel(const float* __restrict__ act,
                                     const float* __restrict__ W,
                                     const float* __restrict__ bias,
                                     float* __restrict__ out) {
    __shared__ float sA2[32][33];
    __shared__ float sB2[32][33];
    int tx = threadIdx.x, ty = threadIdx.y;
    int m = blockIdx.y * 32 + ty;
    int n = blockIdx.x * 32 + tx;
    float acc = 0.f;
    for (int kt = 0; kt < K_DIM; kt += 32) {
        int ka = kt + tx;
        int r = ka >> 10, kl = ka & (KL_ - 1);
        sA2[ty][tx] = act[((size_t)r * M_DIM + m) * KL_ + kl];
        sB2[ty][tx] = W[(size_t)(kt + ty) * N_DIM + n];
        __syncthreads();
        #pragma unroll
        for (int kk = 0; kk < 32; kk++) acc += sA2[ty][kk] * sB2[kk][tx];
        __syncthreads();
    }
    out[(size_t)m * N_DIM + n] = acc + bias[n];
}

extern "C" void kernel_launch(void* const* d_in, const int* in_sizes, int n_in,
                              void* d_out, int out_size, void* d_ws, size_t ws_size,
                              hipStream_t stream) {
    const float* all_act = (const float*)d_in[0];
    const float* local_W = (const float*)d_in[1];
    const float* bias    = (const float*)d_in[2];
    float* out = (float*)d_out;

    const size_t partBytes = (size_t)SPLITK * M_DIM * N_DIM * sizeof(float);  // 67.1 MB
    const size_t elemsA    = (size_t)M_DIM * K_DIM;                           // 33.5M
    const size_t elemsW    = (size_t)K_DIM * N_DIM;                           // 8.4M
    const size_t need = partBytes + elemsA * sizeof(f16) + elemsW * sizeof(f16);  // ~151 MB

    if (ws_size < need) {
        gemm_fallback_kernel<<<dim3(N_DIM / 32, M_DIM / 32), dim3(32, 32), 0, stream>>>(
            all_act, local_W, bias, out);
        return;
    }

    float* part  = (float*)d_ws;
    f16*   Afrag = (f16*)((char*)d_ws + partBytes);
    f16*   Bfrag = Afrag + elemsA;

    conv_a_kernel<<<(M_DIM / 16) * (K_DIM / 32) / 4, 256, 0, stream>>>(all_act, Afrag);
    conv_w_kernel<<<dim3(N_DIM / 64, K_DIM / 64), 256, 0, stream>>>(local_W, Bfrag);
    gemm_frag_kernel<<<256, 512, 0, stream>>>(Afrag, Bfrag, part);
    reduce_kernel<<<MN4 / 256, 256, 0, stream>>>(part, bias, out);
}